// Round 3
// baseline (12673.684 us; speedup 1.0000x reference)
//
#include <hip/hip_runtime.h>

#define TT   128
#define FF   64
#define HH   512
#define GG   2048    // 4H
#define K1   576
#define K2   1024
#define KB1  72      // K1/8
#define KB2  128     // K2/8
#define NBLK 256

using f16x8 = __attribute__((ext_vector_type(8))) _Float16;
using f16x4 = __attribute__((ext_vector_type(4))) _Float16;
using f32x4 = __attribute__((ext_vector_type(4))) float;

// ---------------------------------------------------------------------------
// Repack [U;W] (fp32 [K][2048]) -> MFMA-fragment-native fp16 (validated r1/r2):
// element (ct,kb,c,j) at ((ct*K8+kb)*16+c)*8+j holds B[k=kb*8+j][col], with
// col = (c&3)*512 + ct*4 + (c>>2)  (16-col tiles = 4 h-units x 4 gates).
// ---------------------------------------------------------------------------
__global__ void pack_weights(const float* __restrict__ U, const float* __restrict__ W,
                             const float* __restrict__ bias, int K, int Kh,
                             _Float16* __restrict__ Bp, float* __restrict__ pb)
{
    int K8 = K >> 3;
    int total = K * GG;
    for (int idx = blockIdx.x * blockDim.x + threadIdx.x; idx < total + GG;
         idx += gridDim.x * blockDim.x) {
        if (idx < total) {
            int j = idx & 7, c = (idx >> 3) & 15, rem = idx >> 7;
            int kb = rem % K8, ct = rem / K8;
            int k = kb * 8 + j;
            int col = (c & 3) * HH + ct * 4 + (c >> 2);
            float v = (k < Kh) ? U[k * GG + col] : W[(k - Kh) * GG + col];
            Bp[idx] = (_Float16)v;
        } else {
            int p = idx - total, ct = p >> 4, c = p & 15;
            pb[p] = bias[(c & 3) * HH + ct * 4 + (c >> 2)];
        }
    }
}

// DPP quad_perm broadcast of lane (quad+G): VALU, replaces ds_bpermute shuffles.
template <int CTRL>
__device__ __forceinline__ float qbcast(float v) {
    return __int_as_float(__builtin_amdgcn_mov_dpp(__float_as_int(v), CTRL, 0xF, 0xF, true));
}

// ---------------------------------------------------------------------------
// Gate epilogue. C/D 16x16: col=lane&15, row=(lane>>4)*4+j. Quad lanes
// (l&~3)+{0..3} hold {i,f,cin,o} of one unit -> DPP quad-broadcast gathers.
// cs: [128][33] fp32 (stride 33 -> 16 distinct banks, conflict-free).
// hst: [32][40] fp16 staging panel for coalesced global store.
// ---------------------------------------------------------------------------
__device__ __forceinline__ void lstm_epi(
    f32x4 v4, float bias, float* __restrict__ cs, _Float16* __restrict__ hst,
    int q, int kh, int kq, int c, int ubase)
{
    const int gsel = c & 3, ul = c >> 2;
    const int ub = ubase + ul;
    const int lrow0 = kh * 16 + kq * 4;
#pragma unroll
    for (int j = 0; j < 4; ++j) {
        float v = v4[j] + bias;
        float vi = qbcast<0x00>(v);
        float vf = qbcast<0x55>(v);
        float vc = qbcast<0xAA>(v);
        float vo = qbcast<0xFF>(v);
        float ig = 1.f / (1.f + __expf(-vi));
        float fg = 1.f / (1.f + __expf(-vf));
        float og = 1.f / (1.f + __expf(-vo));
        float cin = vc > 0.f ? vc : 0.f;
        int R = q * 32 + lrow0 + j;
        float cp = cs[R * 33 + ub];
        float cn = fg * cp + ig * cin;
        float hn = og * (cn > 0.f ? cn : 0.f);
        if (gsel == 0) {
            cs[R * 33 + ub] = cn;
            hst[(lrow0 + j) * 40 + ub] = (_Float16)hn;
        }
    }
}

// ---------------------------------------------------------------------------
// Persistent 2-layer LSTM, split-K wave pairs. 256 blocks (1/CU) x 8 waves.
// Block b: rg=b>>4 (128 rows), cg=b&15 (128 gate-cols = 32 units).
// Wave w: pair p=w&3 owns col-tiles ct0=cg*8+2p, ct0+1; kh=w>>2 is the K-half
// (L1: 288 each; L2: 512 each = exactly Q2|Q1). Partials exchanged via LDS;
// wave kh epilogues rowtile kh. Weights: 50 f16x8 = 200 regs/lane.
// ---------------------------------------------------------------------------
__global__ __launch_bounds__(512, 2) void lstm_persist(
    const float* __restrict__ x,
    const _Float16* __restrict__ Bp1, const float* __restrict__ pb1,
    const _Float16* __restrict__ Bp2, const float* __restrict__ pb2,
    const float* __restrict__ Wd, const float* __restrict__ bd,
    _Float16* __restrict__ h1b,   // [2][2048][512]
    _Float16* __restrict__ h2b,   // [2][2048][512]
    unsigned* __restrict__ bar,
    float* __restrict__ out)
{
    __shared__ _Float16 Q1[32][584];    // [h1 512 | x 64 | pad]
    __shared__ _Float16 Q2[32][520];    // [h2 512 | pad]
    __shared__ float    c1s[128 * 33];
    __shared__ float    c2s[128 * 33];
    __shared__ float    xb1[8 * 2 * 64 * 4];   // L1 partial exchange
    __shared__ float    xb2[8 * 2 * 64 * 4];   // L2 partial exchange
    __shared__ _Float16 hst1[32][40];
    __shared__ _Float16 hst2[32][40];

    const int tid = threadIdx.x;
    const int w = tid >> 6, lane = tid & 63;
    const int b = blockIdx.x;
    const int rg = b >> 4, cg = b & 15;
    const int r0 = rg * 128;
    const int p = w & 3, kh = w >> 2;
    const int ct0 = cg * 8 + 2 * p;
    const int c = lane & 15, kq = lane >> 4, kq8 = kq * 8;

    for (int i = tid; i < 128 * 33; i += 512) { c1s[i] = 0.f; c2s[i] = 0.f; }

    // ---- one-time: weight fragments into registers ----
    f16x8 w1f[2][9], w2f[2][16];
#pragma unroll
    for (int ti = 0; ti < 2; ++ti) {
#pragma unroll
        for (int kc = 0; kc < 9; ++kc)
            w1f[ti][kc] = *(const f16x8*)(Bp1 +
                (((size_t)(ct0 + ti) * KB1 + (kh * 9 + kc) * 4 + kq) * 16 + c) * 8);
#pragma unroll
        for (int kc = 0; kc < 16; ++kc)
            w2f[ti][kc] = *(const f16x8*)(Bp2 +
                (((size_t)(ct0 + ti) * KB2 + (kh * 16 + kc) * 4 + kq) * 16 + c) * 8);
    }
    const float bias1[2] = { pb1[ct0 * 16 + c], pb1[(ct0 + 1) * 16 + c] };
    const float bias2[2] = { pb2[ct0 * 16 + c], pb2[(ct0 + 1) * 16 + c] };

    // fixed per-thread LDS row bases
    const _Float16* q1r0 = &Q1[c][0];
    const _Float16* q1r1 = &Q1[16 + c][0];
    const _Float16* qbr0 = kh ? q1r0 : &Q2[c][0];       // L2 k-half source
    const _Float16* qbr1 = kh ? q1r1 : &Q2[16 + c][0];
    __syncthreads();

    for (int s = 0; s <= TT; ++s) {
        const int pr1 = (s + 1) & 1, pw1 = s & 1;
        const int pr2 = s & 1,       pw2 = (s + 1) & 1;
        _Float16* h1w = h1b + (size_t)pw1 * 2048 * HH;
        _Float16* h2w = h2b + (size_t)pw2 * 2048 * HH;

        for (int q = 0; q < 4; ++q) {
            const int gr0 = r0 + q * 32;

            // ---- Phase A: prev-quarter h2 store + stage Q1/Q2/x ----
            if (q > 0 && s > 0 && tid < 128) {
                int row = tid >> 2, ch = tid & 3;
                f16x8 hv = *(const f16x8*)&hst2[row][ch * 8];
                *(f16x8*)(h2w + (size_t)(gr0 - 32 + row) * HH + cg * 32 + ch * 8) = hv;
            }
            {
                const _Float16* src = h1b + ((size_t)pr1 * 2048 + gr0) * HH;
#pragma unroll
                for (int i = tid; i < 2048; i += 512) {
                    int row = i >> 6, ch = (i & 63) * 8;
                    *(f16x8*)&Q1[row][ch] = *(const f16x8*)(src + row * HH + ch);
                }
            }
            if (s < TT) {
                int row = tid >> 4, c4 = (tid & 15) * 4;
                float4 xv = *(const float4*)(x + ((size_t)(gr0 + row) * TT + s) * FF + c4);
                *(f16x4*)&Q1[row][512 + c4] =
                    (f16x4){(_Float16)xv.x, (_Float16)xv.y, (_Float16)xv.z, (_Float16)xv.w};
            }
            if (s > 0) {
                const _Float16* src = h2b + ((size_t)pr2 * 2048 + gr0) * HH;
#pragma unroll
                for (int i = tid; i < 2048; i += 512) {
                    int row = i >> 6, ch = (i & 63) * 8;
                    *(f16x8*)&Q2[row][ch] = *(const f16x8*)(src + row * HH + ch);
                }
            }
            __syncthreads();   // S1

            // ---- Phase B: L1 partial MFMA (k-half), write partner's rowtile ----
            f32x4 accA[2][2];
            if (s < TT) {
#pragma unroll
                for (int rt = 0; rt < 2; ++rt)
#pragma unroll
                    for (int ti = 0; ti < 2; ++ti) accA[rt][ti] = f32x4{0.f, 0.f, 0.f, 0.f};
#pragma unroll
                for (int kc = 0; kc < 9; ++kc) {
                    const int off = (kh * 9 + kc) * 32 + kq8;
                    f16x8 av0 = *(const f16x8*)(q1r0 + off);
                    f16x8 av1 = *(const f16x8*)(q1r1 + off);
                    accA[0][0] = __builtin_amdgcn_mfma_f32_16x16x32_f16(av0, w1f[0][kc], accA[0][0], 0, 0, 0);
                    accA[0][1] = __builtin_amdgcn_mfma_f32_16x16x32_f16(av0, w1f[1][kc], accA[0][1], 0, 0, 0);
                    accA[1][0] = __builtin_amdgcn_mfma_f32_16x16x32_f16(av1, w1f[0][kc], accA[1][0], 0, 0, 0);
                    accA[1][1] = __builtin_amdgcn_mfma_f32_16x16x32_f16(av1, w1f[1][kc], accA[1][1], 0, 0, 0);
                }
                const int rtx = kh ^ 1;
                *(f32x4*)&xb1[((w * 2 + 0) * 64 + lane) * 4] = accA[rtx][0];
                *(f32x4*)&xb1[((w * 2 + 1) * 64 + lane) * 4] = accA[rtx][1];
            }
            __syncthreads();   // S2

            // ---- Phase C: L1 combine+epilogue; L2 partial MFMA + exchange ----
            if (s < TT) {
                f32x4 f0 = accA[kh][0] + *(const f32x4*)&xb1[(((w ^ 4) * 2 + 0) * 64 + lane) * 4];
                f32x4 f1 = accA[kh][1] + *(const f32x4*)&xb1[(((w ^ 4) * 2 + 1) * 64 + lane) * 4];
                lstm_epi(f0, bias1[0], c1s, &hst1[0][0], q, kh, kq, c, (2 * p + 0) * 4);
                lstm_epi(f1, bias1[1], c1s, &hst1[0][0], q, kh, kq, c, (2 * p + 1) * 4);
            }
            f32x4 accB[2][2];
            if (s > 0) {
#pragma unroll
                for (int rt = 0; rt < 2; ++rt)
#pragma unroll
                    for (int ti = 0; ti < 2; ++ti) accB[rt][ti] = f32x4{0.f, 0.f, 0.f, 0.f};
#pragma unroll
                for (int kc = 0; kc < 16; ++kc) {
                    const int off = kc * 32 + kq8;
                    f16x8 av0 = *(const f16x8*)(qbr0 + off);
                    f16x8 av1 = *(const f16x8*)(qbr1 + off);
                    accB[0][0] = __builtin_amdgcn_mfma_f32_16x16x32_f16(av0, w2f[0][kc], accB[0][0], 0, 0, 0);
                    accB[0][1] = __builtin_amdgcn_mfma_f32_16x16x32_f16(av0, w2f[1][kc], accB[0][1], 0, 0, 0);
                    accB[1][0] = __builtin_amdgcn_mfma_f32_16x16x32_f16(av1, w2f[0][kc], accB[1][0], 0, 0, 0);
                    accB[1][1] = __builtin_amdgcn_mfma_f32_16x16x32_f16(av1, w2f[1][kc], accB[1][1], 0, 0, 0);
                }
                const int rtx = kh ^ 1;
                *(f32x4*)&xb2[((w * 2 + 0) * 64 + lane) * 4] = accB[rtx][0];
                *(f32x4*)&xb2[((w * 2 + 1) * 64 + lane) * 4] = accB[rtx][1];
            }
            __syncthreads();   // S3

            // ---- Phase D: h1 coalesced store; L2 combine+epilogue ----
            if (s < TT && tid < 128) {
                int row = tid >> 2, ch = tid & 3;
                f16x8 hv = *(const f16x8*)&hst1[row][ch * 8];
                *(f16x8*)(h1w + (size_t)(gr0 + row) * HH + cg * 32 + ch * 8) = hv;
            }
            if (s > 0) {
                f32x4 f0 = accB[kh][0] + *(const f32x4*)&xb2[(((w ^ 4) * 2 + 0) * 64 + lane) * 4];
                f32x4 f1 = accB[kh][1] + *(const f32x4*)&xb2[(((w ^ 4) * 2 + 1) * 64 + lane) * 4];
                lstm_epi(f0, bias2[0], c2s, &hst2[0][0], q, kh, kq, c, (2 * p + 0) * 4);
                lstm_epi(f1, bias2[1], c2s, &hst2[0][0], q, kh, kq, c, (2 * p + 1) * 4);
            }
            __syncthreads();   // S4
        }
        // last quarter's h2 panel
        if (s > 0 && tid < 128) {
            int row = tid >> 2, ch = tid & 3;
            f16x8 hv = *(const f16x8*)&hst2[row][ch * 8];
            *(f16x8*)(h2w + (size_t)(r0 + 96 + row) * HH + cg * 32 + ch * 8) = hv;
        }

        // ---- grid barrier (monotone counter; 256 co-resident blocks) ----
        if (tid == 0) {
            __threadfence();
            __hip_atomic_fetch_add(bar, 1u, __ATOMIC_ACQ_REL, __HIP_MEMORY_SCOPE_AGENT);
            const unsigned target = (unsigned)NBLK * (unsigned)(s + 1);
            while (__hip_atomic_load(bar, __ATOMIC_ACQUIRE, __HIP_MEMORY_SCOPE_AGENT) < target)
                __builtin_amdgcn_s_sleep(4);
            __threadfence();
        }
        __syncthreads();
    }

    // ---- dense head: out = h2_127 @ Wd + bd (cg==0 blocks; 4 threads/row) ----
    if (cg == 0) {
        const _Float16* hf = h2b + (size_t)((TT + 1) & 1) * 2048 * HH;
        int row = tid >> 2, part = tid & 3;
        const _Float16* hr = hf + (size_t)(r0 + row) * HH + part * 128;
        const float* wd = Wd + part * 128;
        float ssum = 0.f;
#pragma unroll
        for (int u8 = 0; u8 < 16; ++u8) {
            f16x8 hv = *(const f16x8*)(hr + u8 * 8);
#pragma unroll
            for (int k = 0; k < 8; ++k) ssum += (float)hv[k] * wd[u8 * 8 + k];
        }
        ssum += __shfl_xor(ssum, 1);
        ssum += __shfl_xor(ssum, 2);
        if (part == 0) out[r0 + row] = ssum + bd[0];
    }
}

extern "C" void kernel_launch(void* const* d_in, const int* in_sizes, int n_in,
                              void* d_out, int out_size, void* d_ws, size_t ws_size,
                              hipStream_t stream)
{
    const float* x  = (const float*)d_in[0];
    const float* W1 = (const float*)d_in[1];
    const float* U1 = (const float*)d_in[2];
    const float* b1 = (const float*)d_in[3];
    const float* W2 = (const float*)d_in[4];
    const float* U2 = (const float*)d_in[5];
    const float* b2 = (const float*)d_in[6];
    const float* Wd = (const float*)d_in[7];
    const float* bd = (const float*)d_in[8];
    float* out = (float*)d_out;

    char* ws = (char*)d_ws;
    size_t off = 0;
    _Float16* Bp1 = (_Float16*)(ws + off); off += (size_t)K1 * GG * 2;
    _Float16* Bp2 = (_Float16*)(ws + off); off += (size_t)K2 * GG * 2;
    float*    pb1 = (float*)(ws + off);    off += (size_t)GG * 4;
    float*    pb2 = (float*)(ws + off);    off += (size_t)GG * 4;
    _Float16* h1b = (_Float16*)(ws + off); off += (size_t)2 * 2048 * HH * 2;
    _Float16* h2b = (_Float16*)(ws + off); off += (size_t)2 * 2048 * HH * 2;
    unsigned* bar = (unsigned*)(ws + off); off += 256;

    hipMemsetAsync(h1b, 0, (size_t)2 * 2048 * HH * 2, stream);
    hipMemsetAsync(h2b, 0, (size_t)2 * 2048 * HH * 2, stream);
    hipMemsetAsync(bar, 0, 256, stream);

    pack_weights<<<512, 256, 0, stream>>>(U1, W1, b1, K1, HH, Bp1, pb1);
    pack_weights<<<512, 256, 0, stream>>>(U2, W2, b2, K2, HH, Bp2, pb2);
    lstm_persist<<<NBLK, 512, 0, stream>>>(x, Bp1, pb1, Bp2, pb2, Wd, bd,
                                           h1b, h2b, bar, out);
}

// Round 4
// 10360.757 us; speedup vs baseline: 1.2232x; 1.2232x over previous
//
#include <hip/hip_runtime.h>

#define TT   128
#define FF   64
#define HH   512
#define GG   2048    // 4H
#define K1   576
#define K2   1024
#define KB1  72      // K1/8
#define KB2  128     // K2/8
#define NBLK 256

using f16x8 = __attribute__((ext_vector_type(8))) _Float16;
using f16x2 = __attribute__((ext_vector_type(2))) _Float16;
using f32x4 = __attribute__((ext_vector_type(4))) float;

// ---------------------------------------------------------------------------
// Repack [U;W] (fp32 [K][2048]) -> MFMA-fragment-native fp16 (validated r1-r3):
// element (ct,kb,c,j) at ((ct*K8+kb)*16+c)*8+j holds B[k=kb*8+j][col], with
// col = (c&3)*512 + ct*4 + (c>>2)  (16-col tiles = 4 h-units x 4 gates).
// ---------------------------------------------------------------------------
__global__ void pack_weights(const float* __restrict__ U, const float* __restrict__ W,
                             const float* __restrict__ bias, int K, int Kh,
                             _Float16* __restrict__ Bp, float* __restrict__ pb)
{
    int K8 = K >> 3;
    int total = K * GG;
    for (int idx = blockIdx.x * blockDim.x + threadIdx.x; idx < total + GG;
         idx += gridDim.x * blockDim.x) {
        if (idx < total) {
            int j = idx & 7, c = (idx >> 3) & 15, rem = idx >> 7;
            int kb = rem % K8, ct = rem / K8;
            int k = kb * 8 + j;
            int col = (c & 3) * HH + ct * 4 + (c >> 2);
            float v = (k < Kh) ? U[k * GG + col] : W[(k - Kh) * GG + col];
            Bp[idx] = (_Float16)v;
        } else {
            int p = idx - total, ct = p >> 4, c = p & 15;
            pb[p] = bias[(c & 3) * HH + ct * 4 + (c >> 2)];
        }
    }
}

// DPP quad_perm broadcast (VALU; quad = the 4 gates of one unit). Validated r3.
template <int CTRL>
__device__ __forceinline__ float qbcast(float v) {
    return __int_as_float(__builtin_amdgcn_mov_dpp(__float_as_int(v), CTRL, 0xF, 0xF, true));
}

// async global->LDS DMA, 16B/lane; LDS dest = uniform base + lane*16 (linear).
__device__ __forceinline__ void gld_lds16(const _Float16* g, _Float16* l) {
    __builtin_amdgcn_global_load_lds(
        (__attribute__((address_space(1))) const void*)g,
        (__attribute__((address_space(3))) void*)l, 16, 0, 0);
}

// ---------------------------------------------------------------------------
// Gate epilogue. C/D 16x16: col=lane&15, row=kq*4+j. Quad lanes = {i,f,cin,o}
// of one unit. cs stride 33 (conflict-free). hst stride 40 (16B-aligned rows).
// ---------------------------------------------------------------------------
__device__ __forceinline__ void lstm_epi(
    f32x4 v4, float bias, float* __restrict__ cs, _Float16* __restrict__ hstp,
    int R0, int kq, int c, int w)
{
    const int gsel = c & 3, ul = c >> 2;
    const int ublk = w * 4 + ul;
#pragma unroll
    for (int j = 0; j < 4; ++j) {
        float v = v4[j] + bias;
        float vi = qbcast<0x00>(v);
        float vf = qbcast<0x55>(v);
        float vc = qbcast<0xAA>(v);
        float vo = qbcast<0xFF>(v);
        float ig = 1.f / (1.f + __expf(-vi));
        float fg = 1.f / (1.f + __expf(-vf));
        float og = 1.f / (1.f + __expf(-vo));
        float cin = vc > 0.f ? vc : 0.f;
        int Rl = kq * 4 + j;
        int R = R0 + Rl;
        float cp = cs[R * 33 + ublk];
        float cn = fg * cp + ig * cin;
        float hn = og * (cn > 0.f ? cn : 0.f);
        if (gsel == 0) {
            cs[R * 33 + ublk] = cn;
            hstp[Rl * 40 + ublk] = (_Float16)hn;
        }
    }
}

// ---------------------------------------------------------------------------
// Persistent 2-layer LSTM. 256 blocks (1/CU) x 8 waves. Block (rg,cg): 128
// batch rows x 32 units; wave w owns col-tile ct=cg*8+w of BOTH layers,
// weights pinned in 200 VGPRs (asm keep-alive + waves_per_eu(2,2)).
// 16-row chunks, double-buffered, DMA-staged (global_load_lds) with
// XOR-source-permute (chunk^=row&7) so swizzled ds_read_b128 is conflict-free.
// One __syncthreads per chunk. Skew: superstep s = L1@t=s + L2@t=s-1.
// ---------------------------------------------------------------------------
__global__ __attribute__((amdgpu_waves_per_eu(2, 2))) __launch_bounds__(512)
void lstm_persist(
    const float* __restrict__ x,
    const _Float16* __restrict__ Bp1, const float* __restrict__ pb1,
    const _Float16* __restrict__ Bp2, const float* __restrict__ pb2,
    const float* __restrict__ Wd, const float* __restrict__ bd,
    _Float16* __restrict__ h1b,   // [2][2048][512]
    _Float16* __restrict__ h2b,   // [2][2048][512]
    unsigned* __restrict__ bar,
    float* __restrict__ out)
{
    __shared__ _Float16 Q1[2][16 * HH];    // swizzled h1 chunk (rows = 1024B)
    __shared__ _Float16 Q2[2][16 * HH];    // swizzled h2 chunk
    __shared__ _Float16 Xp[2][16][72];     // x_t fp16, 144B rows (16B-aligned)
    __shared__ float    c1s[128 * 33];
    __shared__ float    c2s[128 * 33];
    __shared__ _Float16 hst[2][2][16][40]; // [layer][buf][row][unit]

    const int tid = threadIdx.x;
    const int w = tid >> 6, lane = tid & 63;
    const int b = blockIdx.x;
    const int rg = b >> 4, cg = b & 15;
    const int r0 = rg * 128;
    const int ct = cg * 8 + w;
    const int c = lane & 15, kq = lane >> 4;
    const int swz = (c & 7) << 4;

    for (int i = tid; i < 128 * 33; i += 512) { c1s[i] = 0.f; c2s[i] = 0.f; }

    // ---- one-time: weight fragments -> registers, pinned ----
    f16x8 w1f[18], w2f[32];
#pragma unroll
    for (int kc = 0; kc < 18; ++kc)
        w1f[kc] = *(const f16x8*)(Bp1 + (((size_t)ct * KB1 + kc * 4 + kq) * 16 + c) * 8);
#pragma unroll
    for (int kc = 0; kc < 32; ++kc)
        w2f[kc] = *(const f16x8*)(Bp2 + (((size_t)ct * KB2 + kc * 4 + kq) * 16 + c) * 8);
#pragma unroll
    for (int kc = 0; kc < 18; ++kc) asm volatile("" : "+v"(w1f[kc]));
#pragma unroll
    for (int kc = 0; kc < 32; ++kc) asm volatile("" : "+v"(w2f[kc]));

    const float bias1 = pb1[ct * 16 + c];
    const float bias2 = pb2[ct * 16 + c];

    for (int s = 0; s <= TT; ++s) {
        const int pr1 = (s + 1) & 1, pw1 = s & 1;
        const int pr2 = s & 1,       pw2 = (s + 1) & 1;
        const _Float16* h1r = h1b + (size_t)pr1 * 2048 * HH;
        const _Float16* h2r = h2b + (size_t)pr2 * 2048 * HH;
        _Float16* h1w = h1b + (size_t)pw1 * 2048 * HH;
        _Float16* h2w = h2b + (size_t)pw2 * 2048 * HH;

        // ---- prestage chunk 0 (DMA + x) ----
        {
#pragma unroll
            for (int i = 0; i < 2; ++i) {
                int r = w * 2 + i;
                int sw = (lane ^ (r & 7)) << 3;
                gld_lds16(h1r + (size_t)(r0 + r) * HH + sw, &Q1[0][r * HH]);
                gld_lds16(h2r + (size_t)(r0 + r) * HH + sw, &Q2[0][r * HH]);
            }
            if (s < TT) {
                int row = tid >> 5, col2 = (tid & 31) * 2;
                float2 xv = *(const float2*)(x + ((size_t)(r0 + row) * TT + s) * FF + col2);
                *(f16x2*)&Xp[0][row][col2] = (f16x2){(_Float16)xv.x, (_Float16)xv.y};
            }
        }
        __syncthreads();

        for (int ch = 0; ch < 8; ++ch) {
            const int buf = ch & 1;
            const int R0 = ch * 16;

            // ---- store hst(ch-1) -> global (coalesced 16B) ----
            if (ch >= 1 && tid < 128) {
                int layer = tid >> 6, r = (tid >> 2) & 15, cq = tid & 3;
                bool go = layer ? (s >= 1) : (s < TT);
                if (go) {
                    f16x8 hv = *(const f16x8*)&hst[layer][buf ^ 1][r][cq * 8];
                    _Float16* dst = (layer ? h2w : h1w)
                        + (size_t)(r0 + (ch - 1) * 16 + r) * HH + cg * 32 + cq * 8;
                    *(f16x8*)dst = hv;
                }
            }
            // ---- prefetch chunk ch+1 (DMA; x held in regs) ----
            float2 xnext{0.f, 0.f};
            int xrow = 0, xcol2 = 0;
            bool havex = false;
            if (ch < 7) {
                const int gr = r0 + (ch + 1) * 16;
#pragma unroll
                for (int i = 0; i < 2; ++i) {
                    int r = w * 2 + i;
                    int sw = (lane ^ (r & 7)) << 3;
                    gld_lds16(h1r + (size_t)(gr + r) * HH + sw, &Q1[buf ^ 1][r * HH]);
                    gld_lds16(h2r + (size_t)(gr + r) * HH + sw, &Q2[buf ^ 1][r * HH]);
                }
                if (s < TT) {
                    xrow = tid >> 5; xcol2 = (tid & 31) * 2;
                    xnext = *(const float2*)(x + ((size_t)(gr + xrow) * TT + s) * FF + xcol2);
                    havex = true;
                }
            }

            const char* q1b = (const char*)&Q1[buf][0] + c * 1024;
            const char* q2b = (const char*)&Q2[buf][0] + c * 1024;

            // ---- L1: g = [h1_{s-1} | x_s] @ [U1;W1] ----
            if (s < TT) {
                f32x4 acc{0.f, 0.f, 0.f, 0.f};
#pragma unroll
                for (int kc = 0; kc < 16; ++kc) {
                    f16x8 av = *(const f16x8*)(q1b + ((kc * 64 + kq * 16) ^ swz));
                    acc = __builtin_amdgcn_mfma_f32_16x16x32_f16(av, w1f[kc], acc, 0, 0, 0);
                }
                {
                    f16x8 av = *(const f16x8*)&Xp[buf][c][kq * 8];
                    acc = __builtin_amdgcn_mfma_f32_16x16x32_f16(av, w1f[16], acc, 0, 0, 0);
                    av = *(const f16x8*)&Xp[buf][c][32 + kq * 8];
                    acc = __builtin_amdgcn_mfma_f32_16x16x32_f16(av, w1f[17], acc, 0, 0, 0);
                }
                lstm_epi(acc, bias1, c1s, &hst[0][buf][0][0], R0, kq, c, w);
            }
            // ---- L2: g = [h2_{s-2} | h1_{s-1}] @ [U2;W2] ----
            if (s >= 1) {
                f32x4 acc{0.f, 0.f, 0.f, 0.f};
#pragma unroll
                for (int kc = 0; kc < 16; ++kc) {
                    f16x8 av = *(const f16x8*)(q2b + ((kc * 64 + kq * 16) ^ swz));
                    acc = __builtin_amdgcn_mfma_f32_16x16x32_f16(av, w2f[kc], acc, 0, 0, 0);
                }
#pragma unroll
                for (int kc = 0; kc < 16; ++kc) {
                    f16x8 av = *(const f16x8*)(q1b + ((kc * 64 + kq * 16) ^ swz));
                    acc = __builtin_amdgcn_mfma_f32_16x16x32_f16(av, w2f[16 + kc], acc, 0, 0, 0);
                }
                lstm_epi(acc, bias2, c2s, &hst[1][buf][0][0], R0, kq, c, w);
            }
            // ---- late x write (load issued at top, hidden under compute) ----
            if (havex)
                *(f16x2*)&Xp[buf ^ 1][xrow][xcol2] =
                    (f16x2){(_Float16)xnext.x, (_Float16)xnext.y};

            __syncthreads();   // drains DMA (vmcnt) + LDS writes for next chunk
        }

        // ---- tail: store hst(7) BEFORE grid barrier (visibility for readers) ----
        if (tid < 128) {
            int layer = tid >> 6, r = (tid >> 2) & 15, cq = tid & 3;
            bool go = layer ? (s >= 1) : (s < TT);
            if (go) {
                f16x8 hv = *(const f16x8*)&hst[layer][1][r][cq * 8];
                _Float16* dst = (layer ? h2w : h1w)
                    + (size_t)(r0 + 112 + r) * HH + cg * 32 + cq * 8;
                *(f16x8*)dst = hv;
            }
        }
        __syncthreads();   // all waves' stores drained before tid0's fence

        // ---- grid barrier (monotone counter; 256 co-resident blocks) ----
        if (tid == 0) {
            __threadfence();
            __hip_atomic_fetch_add(bar, 1u, __ATOMIC_ACQ_REL, __HIP_MEMORY_SCOPE_AGENT);
            const unsigned target = (unsigned)NBLK * (unsigned)(s + 1);
            while (__hip_atomic_load(bar, __ATOMIC_ACQUIRE, __HIP_MEMORY_SCOPE_AGENT) < target)
                __builtin_amdgcn_s_sleep(2);
            __threadfence();
        }
        __syncthreads();
    }

    // ---- dense head: out = h2_127 @ Wd + bd (cg==0 blocks; 4 threads/row) ----
    if (cg == 0) {
        const _Float16* hf = h2b + (size_t)((TT + 1) & 1) * 2048 * HH;
        int row = tid >> 2, part = tid & 3;
        const _Float16* hr = hf + (size_t)(r0 + row) * HH + part * 128;
        const float* wd = Wd + part * 128;
        float ssum = 0.f;
#pragma unroll
        for (int u8 = 0; u8 < 16; ++u8) {
            f16x8 hv = *(const f16x8*)(hr + u8 * 8);
#pragma unroll
            for (int k = 0; k < 8; ++k) ssum += (float)hv[k] * wd[u8 * 8 + k];
        }
        ssum += __shfl_xor(ssum, 1);
        ssum += __shfl_xor(ssum, 2);
        if (part == 0) out[r0 + row] = ssum + bd[0];
    }
}

extern "C" void kernel_launch(void* const* d_in, const int* in_sizes, int n_in,
                              void* d_out, int out_size, void* d_ws, size_t ws_size,
                              hipStream_t stream)
{
    const float* x  = (const float*)d_in[0];
    const float* W1 = (const float*)d_in[1];
    const float* U1 = (const float*)d_in[2];
    const float* b1 = (const float*)d_in[3];
    const float* W2 = (const float*)d_in[4];
    const float* U2 = (const float*)d_in[5];
    const float* b2 = (const float*)d_in[6];
    const float* Wd = (const float*)d_in[7];
    const float* bd = (const float*)d_in[8];
    float* out = (float*)d_out;

    char* ws = (char*)d_ws;
    size_t off = 0;
    _Float16* Bp1 = (_Float16*)(ws + off); off += (size_t)K1 * GG * 2;
    _Float16* Bp2 = (_Float16*)(ws + off); off += (size_t)K2 * GG * 2;
    float*    pb1 = (float*)(ws + off);    off += (size_t)GG * 4;
    float*    pb2 = (float*)(ws + off);    off += (size_t)GG * 4;
    _Float16* h1b = (_Float16*)(ws + off); off += (size_t)2 * 2048 * HH * 2;
    _Float16* h2b = (_Float16*)(ws + off); off += (size_t)2 * 2048 * HH * 2;
    unsigned* bar = (unsigned*)(ws + off); off += 256;

    hipMemsetAsync(h1b, 0, (size_t)2 * 2048 * HH * 2, stream);
    hipMemsetAsync(h2b, 0, (size_t)2 * 2048 * HH * 2, stream);
    hipMemsetAsync(bar, 0, 256, stream);

    pack_weights<<<512, 256, 0, stream>>>(U1, W1, b1, K1, HH, Bp1, pb1);
    pack_weights<<<512, 256, 0, stream>>>(U2, W2, b2, K2, HH, Bp2, pb2);
    lstm_persist<<<NBLK, 512, 0, stream>>>(x, Bp1, pb1, Bp2, pb2, Wd, bd,
                                           h1b, h2b, bar, out);
}

// Round 5
// 9654.604 us; speedup vs baseline: 1.3127x; 1.0731x over previous
//
#include <hip/hip_runtime.h>

#define TT   128
#define FF   64
#define HH   512
#define GG   2048    // 4H
#define K1   576
#define K2   1024
#define KB1  72      // K1/8
#define KB2  128     // K2/8
#define NBLK 256

using f16x8 = __attribute__((ext_vector_type(8))) _Float16;
using f16x4 = __attribute__((ext_vector_type(4))) _Float16;
using f32x4 = __attribute__((ext_vector_type(4))) float;

// ---------------------------------------------------------------------------
// Repack [U;W] (fp32 [K][2048]) -> MFMA-fragment-native fp16 (validated r1-r4):
// element (ct,kb,c,j) at ((ct*K8+kb)*16+c)*8+j holds B[k=kb*8+j][col], with
// col = (c&3)*512 + ct*4 + (c>>2)  (16-col tiles = 4 h-units x 4 gates).
// ---------------------------------------------------------------------------
__global__ void pack_weights(const float* __restrict__ U, const float* __restrict__ W,
                             const float* __restrict__ bias, int K, int Kh,
                             _Float16* __restrict__ Bp, float* __restrict__ pb)
{
    int K8 = K >> 3;
    int total = K * GG;
    for (int idx = blockIdx.x * blockDim.x + threadIdx.x; idx < total + GG;
         idx += gridDim.x * blockDim.x) {
        if (idx < total) {
            int j = idx & 7, c = (idx >> 3) & 15, rem = idx >> 7;
            int kb = rem % K8, ct = rem / K8;
            int k = kb * 8 + j;
            int col = (c & 3) * HH + ct * 4 + (c >> 2);
            float v = (k < Kh) ? U[k * GG + col] : W[(k - Kh) * GG + col];
            Bp[idx] = (_Float16)v;
        } else {
            int p = idx - total, ct = p >> 4, c = p & 15;
            pb[p] = bias[(c & 3) * HH + ct * 4 + (c >> 2)];
        }
    }
}

// DPP quad_perm broadcast (VALU; quad = the 4 gates of one unit). Validated r3/r4.
template <int CTRL>
__device__ __forceinline__ float qbcast(float v) {
    return __int_as_float(__builtin_amdgcn_mov_dpp(__float_as_int(v), CTRL, 0xF, 0xF, true));
}

// async global->LDS DMA, 16B/lane; LDS dest = uniform base + lane*16 (linear).
__device__ __forceinline__ void gld_lds16(const _Float16* g, _Float16* l) {
    __builtin_amdgcn_global_load_lds(
        (__attribute__((address_space(1))) const void*)g,
        (__attribute__((address_space(3))) void*)l, 16, 0, 0);
}

// ---------------------------------------------------------------------------
// Gate epilogue (validated r4). C/D 16x16: col=lane&15, row=kq*4+j. Quad lanes
// = {i,f,cin,o} of one unit. cs stride 33 (conflict-free), hst stride 40.
// ---------------------------------------------------------------------------
__device__ __forceinline__ void lstm_epi(
    f32x4 v4, float bias, float* __restrict__ cs, _Float16* __restrict__ hstp,
    int R0, int kq, int c, int ubase)
{
    const int gsel = c & 3;
    const int ub = ubase + (c >> 2);
#pragma unroll
    for (int j = 0; j < 4; ++j) {
        float v = v4[j] + bias;
        float vi = qbcast<0x00>(v);
        float vf = qbcast<0x55>(v);
        float vc = qbcast<0xAA>(v);
        float vo = qbcast<0xFF>(v);
        float ig = 1.f / (1.f + __expf(-vi));
        float fg = 1.f / (1.f + __expf(-vf));
        float og = 1.f / (1.f + __expf(-vo));
        float cin = vc > 0.f ? vc : 0.f;
        int Rl = kq * 4 + j;
        int R = R0 + Rl;
        float cp = cs[R * 33 + ub];
        float cn = fg * cp + ig * cin;
        float hn = og * (cn > 0.f ? cn : 0.f);
        if (gsel == 0) {
            cs[R * 33 + ub] = cn;
            hstp[Rl * 40 + ub] = (_Float16)hn;
        }
    }
}

#define MFMA16(av, bv, acc) \
    acc = __builtin_amdgcn_mfma_f32_16x16x32_f16(av, bv, acc, 0, 0, 0)

// ---------------------------------------------------------------------------
// Persistent 2-layer LSTM. 256 blocks (1/CU) x 256 threads (4 waves, 1/SIMD,
// 512-VGPR budget). Block (rg,cg): 128 rows x 128 gate-cols. Wave (g=w>>1,
// kh=w&1): col-group g (4 tiles = 64 cols), K-half kh; 400 VGPRs of weights.
// L1 split: kh0 = h1[0:288], kh1 = h1[288:512]+x. L2: kh0 = h2, kh1 = h1.
// Partials exchanged via LDS (2 tiles each way); wave kh epilogues tiles
// kh*2+{0,1}. 16-row chunks, DMA-staged double-buffer, 2 syncs/chunk.
// ---------------------------------------------------------------------------
__global__ __launch_bounds__(256, 1) void lstm_persist(
    const float* __restrict__ x,
    const _Float16* __restrict__ Bp1, const float* __restrict__ pb1,
    const _Float16* __restrict__ Bp2, const float* __restrict__ pb2,
    const float* __restrict__ Wd, const float* __restrict__ bd,
    _Float16* __restrict__ h1b,   // [2][2048][512]
    _Float16* __restrict__ h2b,   // [2][2048][512]
    unsigned* __restrict__ bar,
    float* __restrict__ out)
{
    __shared__ _Float16 Q1[2][16 * HH];     // swizzled h1 chunk (1024B rows)
    __shared__ _Float16 Q2[2][16 * HH];     // swizzled h2 chunk
    __shared__ _Float16 Xp[2][16][72];      // x_t fp16 (144B rows)
    __shared__ float    c1s[128 * 33];
    __shared__ float    c2s[128 * 33];
    __shared__ _Float16 hst[2][2][16][40];  // [layer][buf][row][unit]
    __shared__ float    xb[2][2][2][2][256]; // [layer][g][src_kh][j][lane*4]

    const int tid = threadIdx.x;
    const int w = tid >> 6, lane = tid & 63;
    const int g = w >> 1, kh = w & 1;
    const int b = blockIdx.x;
    const int rg = b >> 4, cg = b & 15;
    const int r0 = rg * 128;
    const int c = lane & 15, kq = lane >> 4;
    const int swz = (c & 7) << 4;

    for (int i = tid; i < 128 * 33; i += 256) { c1s[i] = 0.f; c2s[i] = 0.f; }

    // ---- one-time: 400 VGPRs of weight fragments (4 tiles x half-K) ----
    f16x8 w1f[4][9], w2f[4][16];
#pragma unroll
    for (int ti = 0; ti < 4; ++ti) {
        const int ct = cg * 8 + g * 4 + ti;
#pragma unroll
        for (int kc = 0; kc < 9; ++kc)
            w1f[ti][kc] = *(const f16x8*)(Bp1 +
                (((size_t)ct * KB1 + (kh * 9 + kc) * 4 + kq) * 16 + c) * 8);
#pragma unroll
        for (int kc = 0; kc < 16; ++kc)
            w2f[ti][kc] = *(const f16x8*)(Bp2 +
                (((size_t)ct * KB2 + (kh * 16 + kc) * 4 + kq) * 16 + c) * 8);
    }
#pragma unroll
    for (int ti = 0; ti < 4; ++ti) {
#pragma unroll
        for (int kc = 0; kc < 9; ++kc) asm volatile("" : "+v"(w1f[ti][kc]));
#pragma unroll
        for (int kc = 0; kc < 16; ++kc) asm volatile("" : "+v"(w2f[ti][kc]));
    }

    const int ct0 = cg * 8 + g * 4 + kh * 2;      // first OWN tile
    const float bias1v[2] = { pb1[(ct0 + 0) * 16 + c], pb1[(ct0 + 1) * 16 + c] };
    const float bias2v[2] = { pb2[(ct0 + 0) * 16 + c], pb2[(ct0 + 1) * 16 + c] };
    const int ub0 = (g * 4 + kh * 2) * 4;         // first own unit in block

    for (int s = 0; s <= TT; ++s) {
        const int pr1 = (s + 1) & 1, pw1 = s & 1;
        const int pr2 = s & 1,       pw2 = (s + 1) & 1;
        const _Float16* h1r = h1b + (size_t)pr1 * 2048 * HH;
        const _Float16* h2r = h2b + (size_t)pr2 * 2048 * HH;
        _Float16* h1w = h1b + (size_t)pw1 * 2048 * HH;
        _Float16* h2w = h2b + (size_t)pw2 * 2048 * HH;

        // ---- prestage chunk 0 ----
        {
#pragma unroll
            for (int i = 0; i < 4; ++i) {
                int r = w * 4 + i;
                int sw = (lane ^ (r & 7)) << 3;
                gld_lds16(h1r + (size_t)(r0 + r) * HH + sw, &Q1[0][r * HH]);
                gld_lds16(h2r + (size_t)(r0 + r) * HH + sw, &Q2[0][r * HH]);
            }
            if (s < TT) {
                int row = tid >> 4, c4 = (tid & 15) * 4;
                float4 xv = *(const float4*)(x + ((size_t)(r0 + row) * TT + s) * FF + c4);
                *(f16x4*)&Xp[0][row][c4] =
                    (f16x4){(_Float16)xv.x, (_Float16)xv.y, (_Float16)xv.z, (_Float16)xv.w};
            }
        }
        __syncthreads();

        for (int ch = 0; ch < 8; ++ch) {
            const int buf = ch & 1;
            const int R0 = ch * 16;

            // ---- DMA prefetch chunk ch+1 ----
            if (ch < 7) {
                const int gr = r0 + (ch + 1) * 16;
#pragma unroll
                for (int i = 0; i < 4; ++i) {
                    int r = w * 4 + i;
                    int sw = (lane ^ (r & 7)) << 3;
                    gld_lds16(h1r + (size_t)(gr + r) * HH + sw, &Q1[buf ^ 1][r * HH]);
                    gld_lds16(h2r + (size_t)(gr + r) * HH + sw, &Q2[buf ^ 1][r * HH]);
                }
            }
            float4 xnext{0.f, 0.f, 0.f, 0.f};
            const bool havex = (ch < 7) && (s < TT);
            const int xrow = tid >> 4, xc4 = (tid & 15) * 4;
            if (havex)
                xnext = *(const float4*)(x +
                    ((size_t)(r0 + (ch + 1) * 16 + xrow) * TT + s) * FF + xc4);

            // ---- store hst(ch-1) -> global (coalesced 16B) ----
            if (ch >= 1 && tid < 128) {
                int layer = tid >> 6, r = (tid >> 2) & 15, cq = tid & 3;
                bool go2 = layer ? (s >= 1) : (s < TT);
                if (go2) {
                    f16x8 hv = *(const f16x8*)&hst[layer][buf ^ 1][r][cq * 8];
                    _Float16* dst = (layer ? h2w : h1w)
                        + (size_t)(r0 + (ch - 1) * 16 + r) * HH + cg * 32 + cq * 8;
                    *(f16x8*)dst = hv;
                }
            }

            const char* q1b = (const char*)&Q1[buf][0] + c * 1024;
            const char* q2b = (const char*)&Q2[buf][0] + c * 1024;

            // ---- L1 partial (K-half kh), 4 tiles ----
            f32x4 ownA0{0.f, 0.f, 0.f, 0.f}, ownA1 = ownA0;
            if (s < TT) {
                f32x4 a0{0.f, 0.f, 0.f, 0.f}, a1 = a0, a2 = a0, a3 = a0;
                if (kh == 0) {
#pragma unroll
                    for (int kc = 0; kc < 9; ++kc) {
                        f16x8 av = *(const f16x8*)(q1b + ((kc * 64 + kq * 16) ^ swz));
                        MFMA16(av, w1f[0][kc], a0); MFMA16(av, w1f[1][kc], a1);
                        MFMA16(av, w1f[2][kc], a2); MFMA16(av, w1f[3][kc], a3);
                    }
                    *(f32x4*)&xb[0][g][0][0][lane * 4] = a2;
                    *(f32x4*)&xb[0][g][0][1][lane * 4] = a3;
                    ownA0 = a0; ownA1 = a1;
                } else {
#pragma unroll
                    for (int kc = 0; kc < 7; ++kc) {
                        f16x8 av = *(const f16x8*)(q1b + (((kc + 9) * 64 + kq * 16) ^ swz));
                        MFMA16(av, w1f[0][kc], a0); MFMA16(av, w1f[1][kc], a1);
                        MFMA16(av, w1f[2][kc], a2); MFMA16(av, w1f[3][kc], a3);
                    }
                    {
                        f16x8 av = *(const f16x8*)&Xp[buf][c][kq * 8];
                        MFMA16(av, w1f[0][7], a0); MFMA16(av, w1f[1][7], a1);
                        MFMA16(av, w1f[2][7], a2); MFMA16(av, w1f[3][7], a3);
                    }
                    {
                        f16x8 av = *(const f16x8*)&Xp[buf][c][32 + kq * 8];
                        MFMA16(av, w1f[0][8], a0); MFMA16(av, w1f[1][8], a1);
                        MFMA16(av, w1f[2][8], a2); MFMA16(av, w1f[3][8], a3);
                    }
                    *(f32x4*)&xb[0][g][1][0][lane * 4] = a0;
                    *(f32x4*)&xb[0][g][1][1][lane * 4] = a1;
                    ownA0 = a2; ownA1 = a3;
                }
            }
            // ---- L2 partial (kh0: h2 via Q2; kh1: h1 via Q1) ----
            f32x4 ownB0{0.f, 0.f, 0.f, 0.f}, ownB1 = ownB0;
            if (s >= 1) {
                const char* qb = kh ? q1b : q2b;
                f32x4 b0{0.f, 0.f, 0.f, 0.f}, b1 = b0, b2 = b0, b3 = b0;
#pragma unroll
                for (int kc = 0; kc < 16; ++kc) {
                    f16x8 av = *(const f16x8*)(qb + ((kc * 64 + kq * 16) ^ swz));
                    MFMA16(av, w2f[0][kc], b0); MFMA16(av, w2f[1][kc], b1);
                    MFMA16(av, w2f[2][kc], b2); MFMA16(av, w2f[3][kc], b3);
                }
                if (kh == 0) {
                    *(f32x4*)&xb[1][g][0][0][lane * 4] = b2;
                    *(f32x4*)&xb[1][g][0][1][lane * 4] = b3;
                    ownB0 = b0; ownB1 = b1;
                } else {
                    *(f32x4*)&xb[1][g][1][0][lane * 4] = b0;
                    *(f32x4*)&xb[1][g][1][1][lane * 4] = b1;
                    ownB0 = b2; ownB1 = b3;
                }
            }
            __syncthreads();   // S1: partials visible (also drains DMA ch+1)

            // ---- combine + epilogue (own 2 tiles per layer) ----
            if (s < TT) {
                ownA0 += *(const f32x4*)&xb[0][g][kh ^ 1][0][lane * 4];
                ownA1 += *(const f32x4*)&xb[0][g][kh ^ 1][1][lane * 4];
                lstm_epi(ownA0, bias1v[0], c1s, &hst[0][buf][0][0], R0, kq, c, ub0);
                lstm_epi(ownA1, bias1v[1], c1s, &hst[0][buf][0][0], R0, kq, c, ub0 + 4);
            }
            if (s >= 1) {
                ownB0 += *(const f32x4*)&xb[1][g][kh ^ 1][0][lane * 4];
                ownB1 += *(const f32x4*)&xb[1][g][kh ^ 1][1][lane * 4];
                lstm_epi(ownB0, bias2v[0], c2s, &hst[1][buf][0][0], R0, kq, c, ub0);
                lstm_epi(ownB1, bias2v[1], c2s, &hst[1][buf][0][0], R0, kq, c, ub0 + 4);
            }
            if (havex)
                *(f16x4*)&Xp[buf ^ 1][xrow][xc4] =
                    (f16x4){(_Float16)xnext.x, (_Float16)xnext.y,
                            (_Float16)xnext.z, (_Float16)xnext.w};
            __syncthreads();   // S2: epilogue LDS + Xp writes visible
        }

        // ---- tail: store hst(7) before grid barrier ----
        if (tid < 128) {
            int layer = tid >> 6, r = (tid >> 2) & 15, cq = tid & 3;
            bool go2 = layer ? (s >= 1) : (s < TT);
            if (go2) {
                f16x8 hv = *(const f16x8*)&hst[layer][1][r][cq * 8];
                _Float16* dst = (layer ? h2w : h1w)
                    + (size_t)(r0 + 112 + r) * HH + cg * 32 + cq * 8;
                *(f16x8*)dst = hv;
            }
        }
        __syncthreads();   // all waves' stores drained before tid0's fence

        // ---- grid barrier (monotone counter; 256 co-resident blocks) ----
        if (tid == 0) {
            __threadfence();
            __hip_atomic_fetch_add(bar, 1u, __ATOMIC_ACQ_REL, __HIP_MEMORY_SCOPE_AGENT);
            const unsigned target = (unsigned)NBLK * (unsigned)(s + 1);
            while (__hip_atomic_load(bar, __ATOMIC_ACQUIRE, __HIP_MEMORY_SCOPE_AGENT) < target)
                __builtin_amdgcn_s_sleep(2);
            __threadfence();
        }
        __syncthreads();
    }

    // ---- dense head: out = h2_127 @ Wd + bd (cg==0 blocks; 2 threads/row) ----
    if (cg == 0) {
        const _Float16* hf = h2b + (size_t)((TT + 1) & 1) * 2048 * HH;
        int row = tid >> 1, part = tid & 1;
        const _Float16* hr = hf + (size_t)(r0 + row) * HH + part * 256;
        const float* wd = Wd + part * 256;
        float ssum = 0.f;
#pragma unroll
        for (int u8 = 0; u8 < 32; ++u8) {
            f16x8 hv = *(const f16x8*)(hr + u8 * 8);
#pragma unroll
            for (int k = 0; k < 8; ++k) ssum += (float)hv[k] * wd[u8 * 8 + k];
        }
        ssum += __shfl_xor(ssum, 1);
        if (part == 0) out[r0 + row] = ssum + bd[0];
    }
}

extern "C" void kernel_launch(void* const* d_in, const int* in_sizes, int n_in,
                              void* d_out, int out_size, void* d_ws, size_t ws_size,
                              hipStream_t stream)
{
    const float* x  = (const float*)d_in[0];
    const float* W1 = (const float*)d_in[1];
    const float* U1 = (const float*)d_in[2];
    const float* b1 = (const float*)d_in[3];
    const float* W2 = (const float*)d_in[4];
    const float* U2 = (const float*)d_in[5];
    const float* b2 = (const float*)d_in[6];
    const float* Wd = (const float*)d_in[7];
    const float* bd = (const float*)d_in[8];
    float* out = (float*)d_out;

    char* ws = (char*)d_ws;
    size_t off = 0;
    _Float16* Bp1 = (_Float16*)(ws + off); off += (size_t)K1 * GG * 2;
    _Float16* Bp2 = (_Float16*)(ws + off); off += (size_t)K2 * GG * 2;
    float*    pb1 = (float*)(ws + off);    off += (size_t)GG * 4;
    float*    pb2 = (float*)(ws + off);    off += (size_t)GG * 4;
    _Float16* h1b = (_Float16*)(ws + off); off += (size_t)2 * 2048 * HH * 2;
    _Float16* h2b = (_Float16*)(ws + off); off += (size_t)2 * 2048 * HH * 2;
    unsigned* bar = (unsigned*)(ws + off); off += 256;

    hipMemsetAsync(h1b, 0, (size_t)2 * 2048 * HH * 2, stream);
    hipMemsetAsync(h2b, 0, (size_t)2 * 2048 * HH * 2, stream);
    hipMemsetAsync(bar, 0, 256, stream);

    pack_weights<<<512, 256, 0, stream>>>(U1, W1, b1, K1, HH, Bp1, pb1);
    pack_weights<<<512, 256, 0, stream>>>(U2, W2, b2, K2, HH, Bp2, pb2);
    lstm_persist<<<NBLK, 256, 0, stream>>>(x, Bp1, pb1, Bp2, pb2, Wd, bd,
                                           h1b, h2b, bar, out);
}

// Round 6
// 9006.790 us; speedup vs baseline: 1.4071x; 1.0719x over previous
//
#include <hip/hip_runtime.h>

#define TT   128
#define FF   64
#define HH   512
#define GG   2048    // 4H
#define K1   576
#define K2   1024
#define KB1  72      // K1/8
#define KB2  128     // K2/8
#define NBLK 256

using f16x8 = __attribute__((ext_vector_type(8))) _Float16;
using f16x4 = __attribute__((ext_vector_type(4))) _Float16;
using f32x4 = __attribute__((ext_vector_type(4))) float;

// ---------------------------------------------------------------------------
// Repack [U;W] (fp32 [K][2048]) -> MFMA-fragment-native fp16 (validated r1-r5):
// element (ct,kb,c,j) at ((ct*K8+kb)*16+c)*8+j holds B[k=kb*8+j][col], with
// col = (c&3)*512 + ct*4 + (c>>2)  (16-col tiles = 4 h-units x 4 gates).
// ---------------------------------------------------------------------------
__global__ void pack_weights(const float* __restrict__ U, const float* __restrict__ W,
                             const float* __restrict__ bias, int K, int Kh,
                             _Float16* __restrict__ Bp, float* __restrict__ pb)
{
    int K8 = K >> 3;
    int total = K * GG;
    for (int idx = blockIdx.x * blockDim.x + threadIdx.x; idx < total + GG;
         idx += gridDim.x * blockDim.x) {
        if (idx < total) {
            int j = idx & 7, c = (idx >> 3) & 15, rem = idx >> 7;
            int kb = rem % K8, ct = rem / K8;
            int k = kb * 8 + j;
            int col = (c & 3) * HH + ct * 4 + (c >> 2);
            float v = (k < Kh) ? U[k * GG + col] : W[(k - Kh) * GG + col];
            Bp[idx] = (_Float16)v;
        } else {
            int p = idx - total, ct = p >> 4, c = p & 15;
            pb[p] = bias[(c & 3) * HH + ct * 4 + (c >> 2)];
        }
    }
}

// DPP quad_perm broadcast (VALU; quad = the 4 gates of one unit). Validated r3-r5.
template <int CTRL>
__device__ __forceinline__ float qbcast(float v) {
    return __int_as_float(__builtin_amdgcn_mov_dpp(__float_as_int(v), CTRL, 0xF, 0xF, true));
}

// async global->LDS DMA, 16B/lane; LDS dest = uniform base + lane*16 (linear).
__device__ __forceinline__ void gld_lds16(const _Float16* g, _Float16* l) {
    __builtin_amdgcn_global_load_lds(
        (__attribute__((address_space(1))) const void*)g,
        (__attribute__((address_space(3))) void*)l, 16, 0, 0);
}

// ---------------------------------------------------------------------------
// Gate epilogue (validated r4/r5). C/D 16x16: col=lane&15, row=kq*4+j. Quad
// lanes = {i,f,cin,o} of one unit. cs stride 33 (conflict-free), hst stride 40.
// ---------------------------------------------------------------------------
__device__ __forceinline__ void lstm_epi(
    f32x4 v4, float bias, float* __restrict__ cs, _Float16* __restrict__ hstp,
    int R0, int kq, int c, int ubase)
{
    const int gsel = c & 3;
    const int ub = ubase + (c >> 2);
#pragma unroll
    for (int j = 0; j < 4; ++j) {
        float v = v4[j] + bias;
        float vi = qbcast<0x00>(v);
        float vf = qbcast<0x55>(v);
        float vc = qbcast<0xAA>(v);
        float vo = qbcast<0xFF>(v);
        float ig = 1.f / (1.f + __expf(-vi));
        float fg = 1.f / (1.f + __expf(-vf));
        float og = 1.f / (1.f + __expf(-vo));
        float cin = vc > 0.f ? vc : 0.f;
        int Rl = kq * 4 + j;
        int R = R0 + Rl;
        float cp = cs[R * 33 + ub];
        float cn = fg * cp + ig * cin;
        float hn = og * (cn > 0.f ? cn : 0.f);
        if (gsel == 0) {
            cs[R * 33 + ub] = cn;
            hstp[Rl * 40 + ub] = (_Float16)hn;
        }
    }
}

#define MFMA16(av, bv, acc) \
    acc = __builtin_amdgcn_mfma_f32_16x16x32_f16(av, bv, acc, 0, 0, 0)

// ---------------------------------------------------------------------------
// Persistent 2-layer LSTM. 256 blocks (1/CU) x 256 threads (4 waves, 1/SIMD,
// 512-reg unified budget). Block (rg,cg): 128 rows x 128 gate-cols. Wave
// (g=w>>1, kh=w&1): col-group g (4 tiles = 64 cols), K-half kh.
// Weight residency is explicitly partitioned across the unified file:
//   w2f = 64 f16x8 = 256 regs pinned "+a"  -> fills AGPR a0-a255 exactly
//   w1f = 36 f16x8 = 144 regs pinned "+v"  -> VGPR side: 144+~80 < 256
// (r5 failure: "+v" pins forced 400 values into the 256-entry arch-VGPR
// class -> scratch spill. gfx950 MFMA reads B from AGPR directly.)
// L1 split: kh0 = h1[0:288], kh1 = h1[288:512]+x. L2: kh0 = h2, kh1 = h1.
// Partials exchanged via LDS; wave kh epilogues tiles kh*2+{0,1}.
// 16-row chunks, DMA-staged double-buffer, 2 syncs/chunk.
// ---------------------------------------------------------------------------
__global__ __launch_bounds__(256, 1) void lstm_persist(
    const float* __restrict__ x,
    const _Float16* __restrict__ Bp1, const float* __restrict__ pb1,
    const _Float16* __restrict__ Bp2, const float* __restrict__ pb2,
    const float* __restrict__ Wd, const float* __restrict__ bd,
    _Float16* __restrict__ h1b,   // [2][2048][512]
    _Float16* __restrict__ h2b,   // [2][2048][512]
    unsigned* __restrict__ bar,
    float* __restrict__ out)
{
    __shared__ _Float16 Q1[2][16 * HH];     // swizzled h1 chunk (1024B rows)
    __shared__ _Float16 Q2[2][16 * HH];     // swizzled h2 chunk
    __shared__ _Float16 Xp[2][16][72];      // x_t fp16 (144B rows)
    __shared__ float    c1s[128 * 33];
    __shared__ float    c2s[128 * 33];
    __shared__ _Float16 hst[2][2][16][40];  // [layer][buf][row][unit]
    __shared__ float    xb[2][2][2][2][256]; // [layer][g][src_kh][j][lane*4]

    const int tid = threadIdx.x;
    const int w = tid >> 6, lane = tid & 63;
    const int g = w >> 1, kh = w & 1;
    const int b = blockIdx.x;
    const int rg = b >> 4, cg = b & 15;
    const int r0 = rg * 128;
    const int c = lane & 15, kq = lane >> 4;
    const int swz = (c & 7) << 4;

    for (int i = tid; i < 128 * 33; i += 256) { c1s[i] = 0.f; c2s[i] = 0.f; }

    // ---- one-time: weight fragments; w1f -> VGPRs, w2f -> AGPRs ----
    f16x8 w1f[4][9], w2f[4][16];
#pragma unroll
    for (int ti = 0; ti < 4; ++ti) {
        const int ct = cg * 8 + g * 4 + ti;
#pragma unroll
        for (int kc = 0; kc < 9; ++kc)
            w1f[ti][kc] = *(const f16x8*)(Bp1 +
                (((size_t)ct * KB1 + (kh * 9 + kc) * 4 + kq) * 16 + c) * 8);
#pragma unroll
        for (int kc = 0; kc < 16; ++kc)
            w2f[ti][kc] = *(const f16x8*)(Bp2 +
                (((size_t)ct * KB2 + (kh * 16 + kc) * 4 + kq) * 16 + c) * 8);
    }

    const int ct0 = cg * 8 + g * 4 + kh * 2;      // first OWN tile
    const float bias1v[2] = { pb1[(ct0 + 0) * 16 + c], pb1[(ct0 + 1) * 16 + c] };
    const float bias2v[2] = { pb2[(ct0 + 0) * 16 + c], pb2[(ct0 + 1) * 16 + c] };
    const int ub0 = (g * 4 + kh * 2) * 4;         // first own unit in block

    for (int s = 0; s <= TT; ++s) {
        // re-assert register-class residency each superstep (no codegen cost;
        // prevents RA live-range splits from migrating weights to scratch)
#pragma unroll
        for (int ti = 0; ti < 4; ++ti) {
#pragma unroll
            for (int kc = 0; kc < 9; ++kc) asm volatile("" : "+v"(w1f[ti][kc]));
#pragma unroll
            for (int kc = 0; kc < 16; ++kc) asm volatile("" : "+a"(w2f[ti][kc]));
        }

        const int pr1 = (s + 1) & 1, pw1 = s & 1;
        const int pr2 = s & 1,       pw2 = (s + 1) & 1;
        const _Float16* h1r = h1b + (size_t)pr1 * 2048 * HH;
        const _Float16* h2r = h2b + (size_t)pr2 * 2048 * HH;
        _Float16* h1w = h1b + (size_t)pw1 * 2048 * HH;
        _Float16* h2w = h2b + (size_t)pw2 * 2048 * HH;

        // ---- prestage chunk 0 ----
        {
#pragma unroll
            for (int i = 0; i < 4; ++i) {
                int r = w * 4 + i;
                int sw = (lane ^ (r & 7)) << 3;
                gld_lds16(h1r + (size_t)(r0 + r) * HH + sw, &Q1[0][r * HH]);
                gld_lds16(h2r + (size_t)(r0 + r) * HH + sw, &Q2[0][r * HH]);
            }
            if (s < TT) {
                int row = tid >> 4, c4 = (tid & 15) * 4;
                float4 xv = *(const float4*)(x + ((size_t)(r0 + row) * TT + s) * FF + c4);
                *(f16x4*)&Xp[0][row][c4] =
                    (f16x4){(_Float16)xv.x, (_Float16)xv.y, (_Float16)xv.z, (_Float16)xv.w};
            }
        }
        __syncthreads();

        for (int ch = 0; ch < 8; ++ch) {
            const int buf = ch & 1;
            const int R0 = ch * 16;

            // ---- DMA prefetch chunk ch+1 ----
            if (ch < 7) {
                const int gr = r0 + (ch + 1) * 16;
#pragma unroll
                for (int i = 0; i < 4; ++i) {
                    int r = w * 4 + i;
                    int sw = (lane ^ (r & 7)) << 3;
                    gld_lds16(h1r + (size_t)(gr + r) * HH + sw, &Q1[buf ^ 1][r * HH]);
                    gld_lds16(h2r + (size_t)(gr + r) * HH + sw, &Q2[buf ^ 1][r * HH]);
                }
            }
            float4 xnext{0.f, 0.f, 0.f, 0.f};
            const bool havex = (ch < 7) && (s < TT);
            const int xrow = tid >> 4, xc4 = (tid & 15) * 4;
            if (havex)
                xnext = *(const float4*)(x +
                    ((size_t)(r0 + (ch + 1) * 16 + xrow) * TT + s) * FF + xc4);

            // ---- store hst(ch-1) -> global (coalesced 16B) ----
            if (ch >= 1 && tid < 128) {
                int layer = tid >> 6, r = (tid >> 2) & 15, cq = tid & 3;
                bool go2 = layer ? (s >= 1) : (s < TT);
                if (go2) {
                    f16x8 hv = *(const f16x8*)&hst[layer][buf ^ 1][r][cq * 8];
                    _Float16* dst = (layer ? h2w : h1w)
                        + (size_t)(r0 + (ch - 1) * 16 + r) * HH + cg * 32 + cq * 8;
                    *(f16x8*)dst = hv;
                }
            }

            const char* q1b = (const char*)&Q1[buf][0] + c * 1024;
            const char* q2b = (const char*)&Q2[buf][0] + c * 1024;

            // ---- L1 partial (K-half kh), 4 tiles ----
            f32x4 ownA0{0.f, 0.f, 0.f, 0.f}, ownA1 = ownA0;
            if (s < TT) {
                f32x4 a0{0.f, 0.f, 0.f, 0.f}, a1 = a0, a2 = a0, a3 = a0;
                if (kh == 0) {
#pragma unroll
                    for (int kc = 0; kc < 9; ++kc) {
                        f16x8 av = *(const f16x8*)(q1b + ((kc * 64 + kq * 16) ^ swz));
                        MFMA16(av, w1f[0][kc], a0); MFMA16(av, w1f[1][kc], a1);
                        MFMA16(av, w1f[2][kc], a2); MFMA16(av, w1f[3][kc], a3);
                    }
                    *(f32x4*)&xb[0][g][0][0][lane * 4] = a2;
                    *(f32x4*)&xb[0][g][0][1][lane * 4] = a3;
                    ownA0 = a0; ownA1 = a1;
                } else {
#pragma unroll
                    for (int kc = 0; kc < 7; ++kc) {
                        f16x8 av = *(const f16x8*)(q1b + (((kc + 9) * 64 + kq * 16) ^ swz));
                        MFMA16(av, w1f[0][kc], a0); MFMA16(av, w1f[1][kc], a1);
                        MFMA16(av, w1f[2][kc], a2); MFMA16(av, w1f[3][kc], a3);
                    }
                    {
                        f16x8 av = *(const f16x8*)&Xp[buf][c][kq * 8];
                        MFMA16(av, w1f[0][7], a0); MFMA16(av, w1f[1][7], a1);
                        MFMA16(av, w1f[2][7], a2); MFMA16(av, w1f[3][7], a3);
                    }
                    {
                        f16x8 av = *(const f16x8*)&Xp[buf][c][32 + kq * 8];
                        MFMA16(av, w1f[0][8], a0); MFMA16(av, w1f[1][8], a1);
                        MFMA16(av, w1f[2][8], a2); MFMA16(av, w1f[3][8], a3);
                    }
                    *(f32x4*)&xb[0][g][1][0][lane * 4] = a0;
                    *(f32x4*)&xb[0][g][1][1][lane * 4] = a1;
                    ownA0 = a2; ownA1 = a3;
                }
            }
            // ---- L2 partial (kh0: h2 via Q2; kh1: h1 via Q1) ----
            f32x4 ownB0{0.f, 0.f, 0.f, 0.f}, ownB1 = ownB0;
            if (s >= 1) {
                const char* qb = kh ? q1b : q2b;
                f32x4 b0{0.f, 0.f, 0.f, 0.f}, b1 = b0, b2 = b0, b3 = b0;
#pragma unroll
                for (int kc = 0; kc < 16; ++kc) {
                    f16x8 av = *(const f16x8*)(qb + ((kc * 64 + kq * 16) ^ swz));
                    MFMA16(av, w2f[0][kc], b0); MFMA16(av, w2f[1][kc], b1);
                    MFMA16(av, w2f[2][kc], b2); MFMA16(av, w2f[3][kc], b3);
                }
                if (kh == 0) {
                    *(f32x4*)&xb[1][g][0][0][lane * 4] = b2;
                    *(f32x4*)&xb[1][g][0][1][lane * 4] = b3;
                    ownB0 = b0; ownB1 = b1;
                } else {
                    *(f32x4*)&xb[1][g][1][0][lane * 4] = b0;
                    *(f32x4*)&xb[1][g][1][1][lane * 4] = b1;
                    ownB0 = b2; ownB1 = b3;
                }
            }
            __syncthreads();   // S1: partials visible (also drains DMA ch+1)

            // ---- combine + epilogue (own 2 tiles per layer) ----
            if (s < TT) {
                ownA0 += *(const f32x4*)&xb[0][g][kh ^ 1][0][lane * 4];
                ownA1 += *(const f32x4*)&xb[0][g][kh ^ 1][1][lane * 4];
                lstm_epi(ownA0, bias1v[0], c1s, &hst[0][buf][0][0], R0, kq, c, ub0);
                lstm_epi(ownA1, bias1v[1], c1s, &hst[0][buf][0][0], R0, kq, c, ub0 + 4);
            }
            if (s >= 1) {
                ownB0 += *(const f32x4*)&xb[1][g][kh ^ 1][0][lane * 4];
                ownB1 += *(const f32x4*)&xb[1][g][kh ^ 1][1][lane * 4];
                lstm_epi(ownB0, bias2v[0], c2s, &hst[1][buf][0][0], R0, kq, c, ub0);
                lstm_epi(ownB1, bias2v[1], c2s, &hst[1][buf][0][0], R0, kq, c, ub0 + 4);
            }
            if (havex)
                *(f16x4*)&Xp[buf ^ 1][xrow][xc4] =
                    (f16x4){(_Float16)xnext.x, (_Float16)xnext.y,
                            (_Float16)xnext.z, (_Float16)xnext.w};
            __syncthreads();   // S2: epilogue LDS + Xp writes visible
        }

        // ---- tail: store hst(7) before grid barrier ----
        if (tid < 128) {
            int layer = tid >> 6, r = (tid >> 2) & 15, cq = tid & 3;
            bool go2 = layer ? (s >= 1) : (s < TT);
            if (go2) {
                f16x8 hv = *(const f16x8*)&hst[layer][1][r][cq * 8];
                _Float16* dst = (layer ? h2w : h1w)
                    + (size_t)(r0 + 112 + r) * HH + cg * 32 + cq * 8;
                *(f16x8*)dst = hv;
            }
        }
        __syncthreads();   // all waves' stores drained before tid0's fence

        // ---- grid barrier (monotone counter; 256 co-resident blocks) ----
        if (tid == 0) {
            __threadfence();
            __hip_atomic_fetch_add(bar, 1u, __ATOMIC_ACQ_REL, __HIP_MEMORY_SCOPE_AGENT);
            const unsigned target = (unsigned)NBLK * (unsigned)(s + 1);
            while (__hip_atomic_load(bar, __ATOMIC_ACQUIRE, __HIP_MEMORY_SCOPE_AGENT) < target)
                __builtin_amdgcn_s_sleep(2);
            __threadfence();
        }
        __syncthreads();
    }

    // ---- dense head: out = h2_127 @ Wd + bd (cg==0 blocks; 2 threads/row) ----
    if (cg == 0) {
        const _Float16* hf = h2b + (size_t)((TT + 1) & 1) * 2048 * HH;
        int row = tid >> 1, part = tid & 1;
        const _Float16* hr = hf + (size_t)(r0 + row) * HH + part * 256;
        const float* wd = Wd + part * 256;
        float ssum = 0.f;
#pragma unroll
        for (int u8 = 0; u8 < 32; ++u8) {
            f16x8 hv = *(const f16x8*)(hr + u8 * 8);
#pragma unroll
            for (int k = 0; k < 8; ++k) ssum += (float)hv[k] * wd[u8 * 8 + k];
        }
        ssum += __shfl_xor(ssum, 1);
        if (part == 0) out[r0 + row] = ssum + bd[0];
    }
}

extern "C" void kernel_launch(void* const* d_in, const int* in_sizes, int n_in,
                              void* d_out, int out_size, void* d_ws, size_t ws_size,
                              hipStream_t stream)
{
    const float* x  = (const float*)d_in[0];
    const float* W1 = (const float*)d_in[1];
    const float* U1 = (const float*)d_in[2];
    const float* b1 = (const float*)d_in[3];
    const float* W2 = (const float*)d_in[4];
    const float* U2 = (const float*)d_in[5];
    const float* b2 = (const float*)d_in[6];
    const float* Wd = (const float*)d_in[7];
    const float* bd = (const float*)d_in[8];
    float* out = (float*)d_out;

    char* ws = (char*)d_ws;
    size_t off = 0;
    _Float16* Bp1 = (_Float16*)(ws + off); off += (size_t)K1 * GG * 2;
    _Float16* Bp2 = (_Float16*)(ws + off); off += (size_t)K2 * GG * 2;
    float*    pb1 = (float*)(ws + off);    off += (size_t)GG * 4;
    float*    pb2 = (float*)(ws + off);    off += (size_t)GG * 4;
    _Float16* h1b = (_Float16*)(ws + off); off += (size_t)2 * 2048 * HH * 2;
    _Float16* h2b = (_Float16*)(ws + off); off += (size_t)2 * 2048 * HH * 2;
    unsigned* bar = (unsigned*)(ws + off); off += 256;

    hipMemsetAsync(h1b, 0, (size_t)2 * 2048 * HH * 2, stream);
    hipMemsetAsync(h2b, 0, (size_t)2 * 2048 * HH * 2, stream);
    hipMemsetAsync(bar, 0, 256, stream);

    pack_weights<<<512, 256, 0, stream>>>(U1, W1, b1, K1, HH, Bp1, pb1);
    pack_weights<<<512, 256, 0, stream>>>(U2, W2, b2, K2, HH, Bp2, pb2);
    lstm_persist<<<NBLK, 256, 0, stream>>>(x, Bp1, pb1, Bp2, pb2, Wd, bd,
                                           h1b, h2b, bar, out);
}